// Round 2
// baseline (8120.577 us; speedup 1.0000x reference)
//
#include <hip/hip_runtime.h>
#include <math.h>

// Problem constants (B,T,C)=(4,4096,1024), 16 heads x 64, window 256, rope base 1e4.
#define T_SEQ 4096
#define CDIM  1024
#define HDIM  64
#define WIN   256

// log2(10000)/32 — inv_freq[pi] = 2^(-pi * ROPE_C), pi = pair index 0..31
#define ROPE_C 0.415241012f

// ---------------------------------------------------------------------------
// GEMM: C[M x N] = A[M x K](lda) @ B[K x N](ldb) + bias[N], row-major fp32.
// 64x64 tile per block, 256 threads, 4x4 acc per thread, K-chunk 16.
// do_rope: apply RoPE to columns < 2048 (q and k slots of qkv) in the
// epilogue, using absolute position = output row index. Column tiles are
// 64-wide and head blocks are 64-wide, so the rope branch is block-uniform.
// ---------------------------------------------------------------------------
__global__ __launch_bounds__(256)
void gemm_bias_kernel(const float* __restrict__ A, int lda,
                      const float* __restrict__ Bm, int ldb,
                      const float* __restrict__ bias,
                      float* __restrict__ Cm, int ldc, int K, int do_rope) {
  __shared__ float As[16][68];   // [k][row]
  __shared__ float Bs[16][68];   // [k][col]
  const int tx = threadIdx.x, ty = threadIdx.y;
  const int tid = ty * 16 + tx;
  const int row0 = blockIdx.y * 64, col0 = blockIdx.x * 64;
  const int arow = tid >> 2;          // 0..63
  const int akq  = (tid & 3) << 2;    // 0,4,8,12
  const int brow = tid >> 4;          // 0..15
  const int bcol = (tid & 15) << 2;   // 0..60
  const float* Aptr = A + (size_t)(row0 + arow) * lda + akq;
  const float* Bptr = Bm + (size_t)brow * ldb + col0 + bcol;
  float acc[4][4] = {};
  for (int k0 = 0; k0 < K; k0 += 16) {
    float4 av = *(const float4*)(Aptr + k0);
    float4 bv = *(const float4*)(Bptr + (size_t)k0 * ldb);
    As[akq + 0][arow] = av.x;
    As[akq + 1][arow] = av.y;
    As[akq + 2][arow] = av.z;
    As[akq + 3][arow] = av.w;
    *(float4*)&Bs[brow][bcol] = bv;
    __syncthreads();
#pragma unroll
    for (int kk = 0; kk < 16; ++kk) {
      float4 a = *(const float4*)&As[kk][ty << 2];
      float4 b = *(const float4*)&Bs[kk][tx << 2];
      acc[0][0] = fmaf(a.x, b.x, acc[0][0]);
      acc[0][1] = fmaf(a.x, b.y, acc[0][1]);
      acc[0][2] = fmaf(a.x, b.z, acc[0][2]);
      acc[0][3] = fmaf(a.x, b.w, acc[0][3]);
      acc[1][0] = fmaf(a.y, b.x, acc[1][0]);
      acc[1][1] = fmaf(a.y, b.y, acc[1][1]);
      acc[1][2] = fmaf(a.y, b.z, acc[1][2]);
      acc[1][3] = fmaf(a.y, b.w, acc[1][3]);
      acc[2][0] = fmaf(a.z, b.x, acc[2][0]);
      acc[2][1] = fmaf(a.z, b.y, acc[2][1]);
      acc[2][2] = fmaf(a.z, b.z, acc[2][2]);
      acc[2][3] = fmaf(a.z, b.w, acc[2][3]);
      acc[3][0] = fmaf(a.w, b.x, acc[3][0]);
      acc[3][1] = fmaf(a.w, b.y, acc[3][1]);
      acc[3][2] = fmaf(a.w, b.z, acc[3][2]);
      acc[3][3] = fmaf(a.w, b.w, acc[3][3]);
    }
    __syncthreads();
  }
  const int col = col0 + (tx << 2);
  float4 bb = *(const float4*)&bias[col];
  const bool rope = do_rope && (col0 < 2 * CDIM);
  // pair indices for (x,y) and (z,w) within the 64-wide head block
  const int pi0 = (col & 63) >> 1;
  const float inv0 = exp2f(-(float)pi0 * ROPE_C);
  const float inv1 = exp2f(-(float)(pi0 + 1) * ROPE_C);
#pragma unroll
  for (int i = 0; i < 4; ++i) {
    const int trow = row0 + (ty << 2) + i;
    float4 o;
    o.x = acc[i][0] + bb.x;
    o.y = acc[i][1] + bb.y;
    o.z = acc[i][2] + bb.z;
    o.w = acc[i][3] + bb.w;
    if (rope) {
      const float tpos = (float)(trow & (T_SEQ - 1));  // position within sequence
      float a0 = tpos * inv0, a1 = tpos * inv1;
      float s0 = sinf(a0), c0 = cosf(a0);
      float s1 = sinf(a1), c1 = cosf(a1);
      float x1 = o.x, x2 = o.y;
      o.x = fmaf(x1, c0, -x2 * s0);
      o.y = fmaf(x1, s0,  x2 * c0);
      float x3 = o.z, x4 = o.w;
      o.z = fmaf(x3, c1, -x4 * s1);
      o.w = fmaf(x3, s1,  x4 * c1);
    }
    *(float4*)&Cm[(size_t)trow * ldc + col] = o;
  }
}

// ---------------------------------------------------------------------------
// Windowed attention v2. qkv already has RoPE applied to q,k slots.
// Block = 64 queries of one (b, h, window): grid (64 win-qchunks, 16 H, 4 B)
// = 4096 blocks, 256 threads. Thread (qi = tid>>2, kg = tid&3) owns query
// row qi and the 16 keys {kg + 4i}. Single-pass online softmax; row
// max/sum and final y reduced across the 4 kg-lanes via __shfl_xor (lanes
// are adjacent: tid = qi*4+kg). K chunk (64 rows) staged in LDS with row
// stride 68 -> the 4 kg-groups hit disjoint bank quads (conflict-free);
// V read directly from global (L1/L2 broadcast) to keep the LDS pipe free.
// Output y written in-place over this block's own q slot (no other block
// reads it after launch; k/v slots never written).
// ---------------------------------------------------------------------------
__global__ __launch_bounds__(256)
void attn_kernel(float* __restrict__ qkv) {
  __shared__ float Ks[64][68];   // 17.4 KiB
  const int qc = blockIdx.x;           // window*4 + qchunk
  const int w = qc >> 2, qch = qc & 3;
  const int h = blockIdx.y, b = blockIdx.z;
  const int tid = threadIdx.x;
  const int qi = tid >> 2, kg = tid & 3;
  const int t0 = w * WIN;
  const int tq = t0 + qch * 64 + qi;

  const float* qp = qkv + ((size_t)b * T_SEQ + tq) * (3 * CDIM) + h * HDIM;
  float q[64];
#pragma unroll
  for (int d4 = 0; d4 < 16; ++d4) {
    float4 v = ((const float4*)qp)[d4];
    q[4 * d4 + 0] = v.x; q[4 * d4 + 1] = v.y;
    q[4 * d4 + 2] = v.z; q[4 * d4 + 3] = v.w;
  }

  float y[64] = {};
  float m = -1e30f, l = 0.f;

  const int sr = tid >> 2;             // staging row 0..63
  const int sq = (tid & 3) << 4;       // staging quarter offset 0,16,32,48

  for (int kc = 0; kc < 4; ++kc) {
    // ---- stage K chunk (64 rows) ----
    const float* kp = qkv + ((size_t)b * T_SEQ + t0 + kc * 64 + sr) * (3 * CDIM)
                      + CDIM + h * HDIM + sq;
    __syncthreads();   // previous chunk's reads done
    float4 k0 = ((const float4*)kp)[0];
    float4 k1 = ((const float4*)kp)[1];
    float4 k2 = ((const float4*)kp)[2];
    float4 k3 = ((const float4*)kp)[3];
    *(float4*)&Ks[sr][sq + 0]  = k0;
    *(float4*)&Ks[sr][sq + 4]  = k1;
    *(float4*)&Ks[sr][sq + 8]  = k2;
    *(float4*)&Ks[sr][sq + 12] = k3;
    __syncthreads();

    // ---- scores for this thread's 16 keys ----
    float p[16];
    float cmax = -1e30f;
#pragma unroll
    for (int i = 0; i < 16; ++i) {
      const float* kr = &Ks[kg + 4 * i][0];
      float s = 0.f;
#pragma unroll
      for (int d4 = 0; d4 < 16; ++d4) {
        float4 kk = *(const float4*)(kr + 4 * d4);
        s = fmaf(q[4 * d4 + 0], kk.x, s);
        s = fmaf(q[4 * d4 + 1], kk.y, s);
        s = fmaf(q[4 * d4 + 2], kk.z, s);
        s = fmaf(q[4 * d4 + 3], kk.w, s);
      }
      s *= 0.125f;
      p[i] = s;
      cmax = fmaxf(cmax, s);
    }
    // row max across the 4 kg-lanes
    cmax = fmaxf(cmax, __shfl_xor(cmax, 1));
    cmax = fmaxf(cmax, __shfl_xor(cmax, 2));
    const float mn = fmaxf(m, cmax);
    const float alpha = __expf(m - mn);
    float ps = 0.f;
#pragma unroll
    for (int i = 0; i < 16; ++i) {
      p[i] = __expf(p[i] - mn);
      ps += p[i];
    }
    ps += __shfl_xor(ps, 1);
    ps += __shfl_xor(ps, 2);
    l = l * alpha + ps;
    m = mn;
#pragma unroll
    for (int d = 0; d < 64; ++d) y[d] *= alpha;

    // ---- PV: V straight from global ----
    const float* vbase = qkv + ((size_t)b * T_SEQ + t0 + kc * 64) * (3 * CDIM)
                         + 2 * CDIM + h * HDIM;
#pragma unroll
    for (int i = 0; i < 16; ++i) {
      const float* vr = vbase + (size_t)(kg + 4 * i) * (3 * CDIM);
      const float pi_ = p[i];
#pragma unroll
      for (int d4 = 0; d4 < 16; ++d4) {
        float4 vv = ((const float4*)vr)[d4];
        y[4 * d4 + 0] = fmaf(pi_, vv.x, y[4 * d4 + 0]);
        y[4 * d4 + 1] = fmaf(pi_, vv.y, y[4 * d4 + 1]);
        y[4 * d4 + 2] = fmaf(pi_, vv.z, y[4 * d4 + 2]);
        y[4 * d4 + 3] = fmaf(pi_, vv.w, y[4 * d4 + 3]);
      }
    }
  }

  // reduce partial y across the 4 kg-lanes
#pragma unroll
  for (int d = 0; d < 64; ++d) {
    y[d] += __shfl_xor(y[d], 1);
    y[d] += __shfl_xor(y[d], 2);
  }
  const float rl = 1.f / l;
  // each lane writes its quarter of the row
  float* yp = qkv + ((size_t)b * T_SEQ + tq) * (3 * CDIM) + h * HDIM + kg * 16;
#pragma unroll
  for (int j = 0; j < 4; ++j) {
    float4 o;
    o.x = y[kg * 16 + 4 * j + 0] * rl;
    o.y = y[kg * 16 + 4 * j + 1] * rl;
    o.z = y[kg * 16 + 4 * j + 2] * rl;
    o.w = y[kg * 16 + 4 * j + 3] * rl;
    ((float4*)yp)[j] = o;
  }
}

// ---------------------------------------------------------------------------
// ws layout: qkv fp32 [B*T, 3C] = 192 MiB at offset 0. RoPE is fused into
// the QKV-GEMM epilogue (q,k slots). Attention output y overwrites the q
// slot; out-GEMM reads it with lda=3072.
// ---------------------------------------------------------------------------
extern "C" void kernel_launch(void* const* d_in, const int* in_sizes, int n_in,
                              void* d_out, int out_size, void* d_ws, size_t ws_size,
                              hipStream_t stream) {
  const float* x     = (const float*)d_in[0];
  const float* W_in  = (const float*)d_in[1];
  const float* b_in  = (const float*)d_in[2];
  const float* W_out = (const float*)d_in[3];
  const float* b_out = (const float*)d_in[4];
  float* out = (float*)d_out;
  float* qkv = (float*)d_ws;

  dim3 blk(16, 16);
  // qkv = x @ W_in + b_in, rope fused: [16384 x 3072], K=1024
  gemm_bias_kernel<<<dim3(3072 / 64, 16384 / 64), blk, 0, stream>>>(
      x, CDIM, W_in, 3 * CDIM, b_in, qkv, 3 * CDIM, CDIM, 1);
  // windowed attention, y in-place over q slots
  attn_kernel<<<dim3((T_SEQ / WIN) * 4, 16, 4), 256, 0, stream>>>(qkv);
  // out = y @ W_out + b_out : [16384 x 1024], K=1024, A has lda=3072
  gemm_bias_kernel<<<dim3(CDIM / 64, 16384 / 64), blk, 0, stream>>>(
      qkv, 3 * CDIM, W_out, CDIM, b_out, out, CDIM, CDIM, 0);
}

// Round 3
// 2780.906 us; speedup vs baseline: 2.9201x; 2.9201x over previous
//
#include <hip/hip_runtime.h>
#include <math.h>

// Problem constants (B,T,C)=(4,4096,1024), 16 heads x 64, window 256, rope base 1e4.
#define T_SEQ 4096
#define CDIM  1024
#define HDIM  64
#define WIN   256

// log2(10000)/32 — inv_freq[pi] = 2^(-pi * ROPE_C), pi = pair index 0..31
#define ROPE_C 0.415241012f

typedef __attribute__((ext_vector_type(8))) short short8;
typedef __attribute__((ext_vector_type(4))) float float4v;

// round-to-nearest-even fp32 -> bf16 (as ushort)
__device__ __forceinline__ unsigned int f2bf(float f) {
  unsigned int u = __float_as_uint(f);
  u += 0x7fffu + ((u >> 16) & 1u);
  return u >> 16;
}

// W^T bf16 accessor. blocked=0: linear [N][K] at wt. blocked=1: packed into the
// dead k/v columns of qkv rows (4096 bf16 per qkv row at float-offset 1024).
__device__ __forceinline__ uint4 wt_ld16(const unsigned short* wt, const float* qkvb,
                                         int blocked, long i) {
  if (!blocked) return *(const uint4*)(wt + i);
  const unsigned short* p =
      (const unsigned short*)(qkvb + (i >> 12) * 3072 + 1024) + (i & 4095);
  return *(const uint4*)p;
}

// ---------------------------------------------------------------------------
// Transpose + convert: W fp32 [K][N] row-major -> W^T bf16 [N][K].
// 32x32 tiles via LDS. blocked selects the qkv-dead-column packing.
// ---------------------------------------------------------------------------
__global__ __launch_bounds__(256)
void transpose_cvt(const float* __restrict__ W, unsigned short* __restrict__ dst,
                   float* __restrict__ qkvb, int blocked, int K, int N) {
  __shared__ float tile[32][33];
  const int tid = threadIdx.x;
  const int ktile = blockIdx.y * 32, ntile = blockIdx.x * 32;
  const int kl = tid >> 3, nl4 = (tid & 7) * 4;
  float4 v = *(const float4*)&W[(size_t)(ktile + kl) * N + ntile + nl4];
  tile[nl4 + 0][kl] = v.x;
  tile[nl4 + 1][kl] = v.y;
  tile[nl4 + 2][kl] = v.z;
  tile[nl4 + 3][kl] = v.w;
  __syncthreads();
  const int nl = tid >> 3, kl4 = (tid & 7) * 4;
  uint2 pk;
  pk.x = f2bf(tile[nl][kl4 + 0]) | (f2bf(tile[nl][kl4 + 1]) << 16);
  pk.y = f2bf(tile[nl][kl4 + 2]) | (f2bf(tile[nl][kl4 + 3]) << 16);
  long i = (long)(ntile + nl) * K + ktile + kl4;
  if (!blocked) {
    *(uint2*)(dst + i) = pk;
  } else {
    unsigned short* p = (unsigned short*)(qkvb + (i >> 12) * 3072 + 1024) + (i & 4095);
    *(uint2*)p = pk;
  }
}

// ---------------------------------------------------------------------------
// bf16 MFMA GEMM: C[M x N] = A[M x K] (fp32, lda) @ W (via W^T bf16) + bias.
// 128x128 block, 256 threads = 4 waves in 2x2, each wave 64x64 (4x4 tiles of
// 16x16x32 mfma). BK=32. LDS rows = 32 bf16 (64B) with XOR swizzle on 16B
// chunks: c' = c ^ ((row>>1)&3) -> conflict-free b128 frag reads.
// A is converted fp32->bf16 during staging. do_rope applies RoPE to cols<2048.
// ---------------------------------------------------------------------------
__global__ __launch_bounds__(256)
void gemm_mfma(const float* __restrict__ A, int lda,
               const unsigned short* __restrict__ wt, const float* __restrict__ wtq,
               int blocked, const float* __restrict__ bias,
               float* __restrict__ Cm, int ldc, int K, int do_rope) {
  __shared__ unsigned short As[128 * 32];
  __shared__ unsigned short Bs[128 * 32];
  const int t = threadIdx.x;
  const int row0 = blockIdx.y * 128, col0 = blockIdx.x * 128;
  const int lane = t & 63, wave = t >> 6;
  const int wm = (wave >> 1) * 64, wn = (wave & 1) * 64;
  const int l15 = lane & 15, quad = lane >> 4;

  // staging assignment: thread covers row sm, 16-bf16 half sk
  const int sm = t >> 1;
  const int sk = (t & 1) * 16;
  const int swz = (sm >> 1) & 3;
  const int c0 = ((t & 1) * 2 + 0) ^ swz;
  const int c1 = ((t & 1) * 2 + 1) ^ swz;
  const float* ap = A + (size_t)(row0 + sm) * lda + sk;
  const long bi = (long)(col0 + sm) * K + sk;

  float4v acc[4][4];
#pragma unroll
  for (int i = 0; i < 4; ++i)
#pragma unroll
    for (int j = 0; j < 4; ++j) acc[i][j] = (float4v){0.f, 0.f, 0.f, 0.f};

  for (int k0 = 0; k0 < K; k0 += 32) {
    float4 a0 = *(const float4*)(ap + k0);
    float4 a1 = *(const float4*)(ap + k0 + 4);
    float4 a2 = *(const float4*)(ap + k0 + 8);
    float4 a3 = *(const float4*)(ap + k0 + 12);
    uint4 bv0 = wt_ld16(wt, wtq, blocked, bi + k0);
    uint4 bv1 = wt_ld16(wt, wtq, blocked, bi + k0 + 8);
    uint4 pa0, pa1;
    pa0.x = f2bf(a0.x) | (f2bf(a0.y) << 16);
    pa0.y = f2bf(a0.z) | (f2bf(a0.w) << 16);
    pa0.z = f2bf(a1.x) | (f2bf(a1.y) << 16);
    pa0.w = f2bf(a1.z) | (f2bf(a1.w) << 16);
    pa1.x = f2bf(a2.x) | (f2bf(a2.y) << 16);
    pa1.y = f2bf(a2.z) | (f2bf(a2.w) << 16);
    pa1.z = f2bf(a3.x) | (f2bf(a3.y) << 16);
    pa1.w = f2bf(a3.z) | (f2bf(a3.w) << 16);
    __syncthreads();  // previous iteration's frag reads complete
    *(uint4*)&As[sm * 32 + c0 * 8] = pa0;
    *(uint4*)&As[sm * 32 + c1 * 8] = pa1;
    *(uint4*)&Bs[sm * 32 + c0 * 8] = bv0;
    *(uint4*)&Bs[sm * 32 + c1 * 8] = bv1;
    __syncthreads();
    short8 af[4], bfr[4];
#pragma unroll
    for (int mt = 0; mt < 4; ++mt) {
      const int r = wm + mt * 16 + l15;
      af[mt] = *(const short8*)&As[r * 32 + (quad ^ ((r >> 1) & 3)) * 8];
    }
#pragma unroll
    for (int nt = 0; nt < 4; ++nt) {
      const int r = wn + nt * 16 + l15;
      bfr[nt] = *(const short8*)&Bs[r * 32 + (quad ^ ((r >> 1) & 3)) * 8];
    }
#pragma unroll
    for (int mt = 0; mt < 4; ++mt)
#pragma unroll
      for (int nt = 0; nt < 4; ++nt)
        acc[mt][nt] = __builtin_amdgcn_mfma_f32_16x16x32_bf16(af[mt], bfr[nt],
                                                              acc[mt][nt], 0, 0, 0);
  }

  // epilogue: C/D layout col = lane&15, row = quad*4 + reg
#pragma unroll
  for (int nt = 0; nt < 4; ++nt) {
    const int col = col0 + wn + nt * 16 + l15;
    const float bb = bias[col];
    const bool rope = do_rope && (col < 2 * CDIM);
    const int pi = (col & 63) >> 1;
    const float inv = exp2f(-(float)pi * ROPE_C);
    const float sgn = (col & 1) ? 1.f : -1.f;
#pragma unroll
    for (int mt = 0; mt < 4; ++mt) {
#pragma unroll
      for (int r = 0; r < 4; ++r) {
        const int row = row0 + wm + mt * 16 + quad * 4 + r;
        float v = acc[mt][nt][r] + bb;
        float vp = __shfl_xor(v, 1);  // rope partner (adjacent column)
        if (rope) {
          const float tpos = (float)(row & (T_SEQ - 1));
          const float ang = tpos * inv;
          const float s = sinf(ang), c = cosf(ang);
          v = v * c + sgn * vp * s;
        }
        Cm[(size_t)row * ldc + col] = v;
      }
    }
  }
}

// ---------------------------------------------------------------------------
// Windowed attention (R2 structure, spill-fixed epilogue). qkv has RoPE
// pre-applied to q,k. Block = 64 queries of one (b,h,window); thread
// (qi=tid>>2, kg=tid&3) owns query row qi and keys {kg+4i}. Single-pass
// online softmax, 4-lane shfl reductions. K chunks staged in LDS; V read
// from global. y written in-place over the q slot.
// Epilogue uses compile-time seg branches: NO dynamic register indexing
// (R2's y[kg*16+..] dynamic index spilled y[] to scratch -> 27 GB traffic).
// ---------------------------------------------------------------------------
__global__ __launch_bounds__(256)
void attn_kernel(float* __restrict__ qkv) {
  __shared__ float Ks[64][68];
  const int qc = blockIdx.x;
  const int w = qc >> 2, qch = qc & 3;
  const int h = blockIdx.y, b = blockIdx.z;
  const int tid = threadIdx.x;
  const int qi = tid >> 2, kg = tid & 3;
  const int t0 = w * WIN;
  const int tq = t0 + qch * 64 + qi;

  const float* qp = qkv + ((size_t)b * T_SEQ + tq) * (3 * CDIM) + h * HDIM;
  float q[64];
#pragma unroll
  for (int d4 = 0; d4 < 16; ++d4) {
    float4 v = ((const float4*)qp)[d4];
    q[4 * d4 + 0] = v.x; q[4 * d4 + 1] = v.y;
    q[4 * d4 + 2] = v.z; q[4 * d4 + 3] = v.w;
  }

  float y[64] = {};
  float m = -1e30f, l = 0.f;

  const int sr = tid >> 2;
  const int sq = (tid & 3) << 4;

  for (int kc = 0; kc < 4; ++kc) {
    const float* kp = qkv + ((size_t)b * T_SEQ + t0 + kc * 64 + sr) * (3 * CDIM)
                      + CDIM + h * HDIM + sq;
    __syncthreads();
    float4 k0 = ((const float4*)kp)[0];
    float4 k1 = ((const float4*)kp)[1];
    float4 k2 = ((const float4*)kp)[2];
    float4 k3 = ((const float4*)kp)[3];
    *(float4*)&Ks[sr][sq + 0]  = k0;
    *(float4*)&Ks[sr][sq + 4]  = k1;
    *(float4*)&Ks[sr][sq + 8]  = k2;
    *(float4*)&Ks[sr][sq + 12] = k3;
    __syncthreads();

    float p[16];
    float cmax = -1e30f;
#pragma unroll
    for (int i = 0; i < 16; ++i) {
      const float* kr = &Ks[kg + 4 * i][0];
      float s = 0.f;
#pragma unroll
      for (int d4 = 0; d4 < 16; ++d4) {
        float4 kk = *(const float4*)(kr + 4 * d4);
        s = fmaf(q[4 * d4 + 0], kk.x, s);
        s = fmaf(q[4 * d4 + 1], kk.y, s);
        s = fmaf(q[4 * d4 + 2], kk.z, s);
        s = fmaf(q[4 * d4 + 3], kk.w, s);
      }
      s *= 0.125f;
      p[i] = s;
      cmax = fmaxf(cmax, s);
    }
    cmax = fmaxf(cmax, __shfl_xor(cmax, 1));
    cmax = fmaxf(cmax, __shfl_xor(cmax, 2));
    const float mn = fmaxf(m, cmax);
    const float alpha = __expf(m - mn);
    float ps = 0.f;
#pragma unroll
    for (int i = 0; i < 16; ++i) {
      p[i] = __expf(p[i] - mn);
      ps += p[i];
    }
    ps += __shfl_xor(ps, 1);
    ps += __shfl_xor(ps, 2);
    l = l * alpha + ps;
    m = mn;
#pragma unroll
    for (int d = 0; d < 64; ++d) y[d] *= alpha;

    const float* vbase = qkv + ((size_t)b * T_SEQ + t0 + kc * 64) * (3 * CDIM)
                         + 2 * CDIM + h * HDIM;
#pragma unroll
    for (int i = 0; i < 16; ++i) {
      const float* vr = vbase + (size_t)(kg + 4 * i) * (3 * CDIM);
      const float pi_ = p[i];
#pragma unroll
      for (int d4 = 0; d4 < 16; ++d4) {
        float4 vv = ((const float4*)vr)[d4];
        y[4 * d4 + 0] = fmaf(pi_, vv.x, y[4 * d4 + 0]);
        y[4 * d4 + 1] = fmaf(pi_, vv.y, y[4 * d4 + 1]);
        y[4 * d4 + 2] = fmaf(pi_, vv.z, y[4 * d4 + 2]);
        y[4 * d4 + 3] = fmaf(pi_, vv.w, y[4 * d4 + 3]);
      }
    }
  }

#pragma unroll
  for (int d = 0; d < 64; ++d) {
    y[d] += __shfl_xor(y[d], 1);
    y[d] += __shfl_xor(y[d], 2);
  }
  const float rl = 1.f / l;
  float* yrow = qkv + ((size_t)b * T_SEQ + tq) * (3 * CDIM) + h * HDIM;
  // compile-time seg: every y[] index is a constant -> no scratch spill
#pragma unroll
  for (int seg = 0; seg < 4; ++seg) {
    if (kg == seg) {
      float* yp = yrow + seg * 16;
#pragma unroll
      for (int j = 0; j < 4; ++j) {
        float4 o;
        o.x = y[seg * 16 + 4 * j + 0] * rl;
        o.y = y[seg * 16 + 4 * j + 1] * rl;
        o.z = y[seg * 16 + 4 * j + 2] * rl;
        o.w = y[seg * 16 + 4 * j + 3] * rl;
        ((float4*)yp)[j] = o;
      }
    }
  }
}

// ---------------------------------------------------------------------------
// ws: qkv fp32 [16384 x 3072] = 192 MiB. W_inT bf16 (6 MiB) lives in d_out
// (dead before the final GEMM overwrites d_out). W_outT bf16 (2 MiB) lives in
// the dead k/v columns of qkv rows 0..255 (dead only AFTER attention, so its
// transpose launches between attn and the out-GEMM).
// ---------------------------------------------------------------------------
extern "C" void kernel_launch(void* const* d_in, const int* in_sizes, int n_in,
                              void* d_out, int out_size, void* d_ws, size_t ws_size,
                              hipStream_t stream) {
  const float* x     = (const float*)d_in[0];
  const float* W_in  = (const float*)d_in[1];
  const float* b_in  = (const float*)d_in[2];
  const float* W_out = (const float*)d_in[3];
  const float* b_out = (const float*)d_in[4];
  float* out = (float*)d_out;
  float* qkv = (float*)d_ws;
  unsigned short* winT = (unsigned short*)d_out;  // first 6 MiB of d_out

  // W_in^T bf16 -> d_out scratch
  transpose_cvt<<<dim3(3072 / 32, 1024 / 32), 256, 0, stream>>>(
      W_in, winT, nullptr, 0, 1024, 3072);
  // qkv = x @ W_in + b_in, rope fused on cols<2048
  gemm_mfma<<<dim3(3072 / 128, 16384 / 128), 256, 0, stream>>>(
      x, CDIM, winT, nullptr, 0, b_in, qkv, 3 * CDIM, CDIM, 1);
  // windowed attention, y in-place over q slots
  attn_kernel<<<dim3((T_SEQ / WIN) * 4, 16, 4), 256, 0, stream>>>(qkv);
  // W_out^T bf16 -> dead k/v columns of qkv (safe only after attn)
  transpose_cvt<<<dim3(1024 / 32, 1024 / 32), 256, 0, stream>>>(
      W_out, nullptr, qkv, 1, 1024, 1024);
  // out = y @ W_out + b_out
  gemm_mfma<<<dim3(1024 / 128, 16384 / 128), 256, 0, stream>>>(
      qkv, 3 * CDIM, nullptr, qkv, 1, b_out, out, CDIM, CDIM, 0);
}

// Round 4
// 761.214 us; speedup vs baseline: 10.6679x; 3.6532x over previous
//
#include <hip/hip_runtime.h>
#include <math.h>

// Problem constants (B,T,C)=(4,4096,1024), 16 heads x 64, window 256, rope base 1e4.
#define T_SEQ 4096
#define CDIM  1024
#define HDIM  64
#define WIN   256

// log2(10000)/32 — inv_freq[pi] = 2^(-pi * ROPE_C), pi = pair index 0..31
#define ROPE_C 0.415241012f
// 0.125 * log2(e): softmax computed in exp2 domain
#define SCALE_LOG2E 0.1803368801f

typedef __attribute__((ext_vector_type(8))) short short8;
typedef __attribute__((ext_vector_type(4))) float float4v;

// round-to-nearest-even fp32 -> bf16 (as ushort)
__device__ __forceinline__ unsigned int f2bf(float f) {
  unsigned int u = __float_as_uint(f);
  u += 0x7fffu + ((u >> 16) & 1u);
  return u >> 16;
}

// W^T bf16 accessor. blocked=0: linear [N][K] at wt. blocked=1: packed into the
// dead k/v columns of qkv rows (4096 bf16 per qkv row at float-offset 1024).
__device__ __forceinline__ uint4 wt_ld16(const unsigned short* wt, const float* qkvb,
                                         int blocked, long i) {
  if (!blocked) return *(const uint4*)(wt + i);
  const unsigned short* p =
      (const unsigned short*)(qkvb + (i >> 12) * 3072 + 1024) + (i & 4095);
  return *(const uint4*)p;
}

// ---------------------------------------------------------------------------
// Transpose + convert: W fp32 [K][N] row-major -> W^T bf16 [N][K].
// ---------------------------------------------------------------------------
__global__ __launch_bounds__(256)
void transpose_cvt(const float* __restrict__ W, unsigned short* __restrict__ dst,
                   float* __restrict__ qkvb, int blocked, int K, int N) {
  __shared__ float tile[32][33];
  const int tid = threadIdx.x;
  const int ktile = blockIdx.y * 32, ntile = blockIdx.x * 32;
  const int kl = tid >> 3, nl4 = (tid & 7) * 4;
  float4 v = *(const float4*)&W[(size_t)(ktile + kl) * N + ntile + nl4];
  tile[nl4 + 0][kl] = v.x;
  tile[nl4 + 1][kl] = v.y;
  tile[nl4 + 2][kl] = v.z;
  tile[nl4 + 3][kl] = v.w;
  __syncthreads();
  const int nl = tid >> 3, kl4 = (tid & 7) * 4;
  uint2 pk;
  pk.x = f2bf(tile[nl][kl4 + 0]) | (f2bf(tile[nl][kl4 + 1]) << 16);
  pk.y = f2bf(tile[nl][kl4 + 2]) | (f2bf(tile[nl][kl4 + 3]) << 16);
  long i = (long)(ntile + nl) * K + ktile + kl4;
  if (!blocked) {
    *(uint2*)(dst + i) = pk;
  } else {
    unsigned short* p = (unsigned short*)(qkvb + (i >> 12) * 3072 + 1024) + (i & 4095);
    *(uint2*)p = pk;
  }
}

// ---------------------------------------------------------------------------
// bf16 MFMA GEMM (unchanged from R3): C = A[fp32] @ W^T(bf16) + bias, 128x128
// block, 4 waves, 16x16x32 mfma, XOR-swizzled LDS. RoPE fused on cols<2048.
// ---------------------------------------------------------------------------
__global__ __launch_bounds__(256)
void gemm_mfma(const float* __restrict__ A, int lda,
               const unsigned short* __restrict__ wt, const float* __restrict__ wtq,
               int blocked, const float* __restrict__ bias,
               float* __restrict__ Cm, int ldc, int K, int do_rope) {
  __shared__ unsigned short As[128 * 32];
  __shared__ unsigned short Bs[128 * 32];
  const int t = threadIdx.x;
  const int row0 = blockIdx.y * 128, col0 = blockIdx.x * 128;
  const int lane = t & 63, wave = t >> 6;
  const int wm = (wave >> 1) * 64, wn = (wave & 1) * 64;
  const int l15 = lane & 15, quad = lane >> 4;

  const int sm = t >> 1;
  const int sk = (t & 1) * 16;
  const int swz = (sm >> 1) & 3;
  const int c0 = ((t & 1) * 2 + 0) ^ swz;
  const int c1 = ((t & 1) * 2 + 1) ^ swz;
  const float* ap = A + (size_t)(row0 + sm) * lda + sk;
  const long bi = (long)(col0 + sm) * K + sk;

  float4v acc[4][4];
#pragma unroll
  for (int i = 0; i < 4; ++i)
#pragma unroll
    for (int j = 0; j < 4; ++j) acc[i][j] = (float4v){0.f, 0.f, 0.f, 0.f};

  for (int k0 = 0; k0 < K; k0 += 32) {
    float4 a0 = *(const float4*)(ap + k0);
    float4 a1 = *(const float4*)(ap + k0 + 4);
    float4 a2 = *(const float4*)(ap + k0 + 8);
    float4 a3 = *(const float4*)(ap + k0 + 12);
    uint4 bv0 = wt_ld16(wt, wtq, blocked, bi + k0);
    uint4 bv1 = wt_ld16(wt, wtq, blocked, bi + k0 + 8);
    uint4 pa0, pa1;
    pa0.x = f2bf(a0.x) | (f2bf(a0.y) << 16);
    pa0.y = f2bf(a0.z) | (f2bf(a0.w) << 16);
    pa0.z = f2bf(a1.x) | (f2bf(a1.y) << 16);
    pa0.w = f2bf(a1.z) | (f2bf(a1.w) << 16);
    pa1.x = f2bf(a2.x) | (f2bf(a2.y) << 16);
    pa1.y = f2bf(a2.z) | (f2bf(a2.w) << 16);
    pa1.z = f2bf(a3.x) | (f2bf(a3.y) << 16);
    pa1.w = f2bf(a3.z) | (f2bf(a3.w) << 16);
    __syncthreads();
    *(uint4*)&As[sm * 32 + c0 * 8] = pa0;
    *(uint4*)&As[sm * 32 + c1 * 8] = pa1;
    *(uint4*)&Bs[sm * 32 + c0 * 8] = bv0;
    *(uint4*)&Bs[sm * 32 + c1 * 8] = bv1;
    __syncthreads();
    short8 af[4], bfr[4];
#pragma unroll
    for (int mt = 0; mt < 4; ++mt) {
      const int r = wm + mt * 16 + l15;
      af[mt] = *(const short8*)&As[r * 32 + (quad ^ ((r >> 1) & 3)) * 8];
    }
#pragma unroll
    for (int nt = 0; nt < 4; ++nt) {
      const int r = wn + nt * 16 + l15;
      bfr[nt] = *(const short8*)&Bs[r * 32 + (quad ^ ((r >> 1) & 3)) * 8];
    }
#pragma unroll
    for (int mt = 0; mt < 4; ++mt)
#pragma unroll
      for (int nt = 0; nt < 4; ++nt)
        acc[mt][nt] = __builtin_amdgcn_mfma_f32_16x16x32_bf16(af[mt], bfr[nt],
                                                              acc[mt][nt], 0, 0, 0);
  }

#pragma unroll
  for (int nt = 0; nt < 4; ++nt) {
    const int col = col0 + wn + nt * 16 + l15;
    const float bb = bias[col];
    const bool rope = do_rope && (col < 2 * CDIM);
    const int pi = (col & 63) >> 1;
    const float inv = exp2f(-(float)pi * ROPE_C);
    const float sgn = (col & 1) ? 1.f : -1.f;
#pragma unroll
    for (int mt = 0; mt < 4; ++mt) {
#pragma unroll
      for (int r = 0; r < 4; ++r) {
        const int row = row0 + wm + mt * 16 + quad * 4 + r;
        float v = acc[mt][nt][r] + bb;
        float vp = __shfl_xor(v, 1);
        if (rope) {
          const float tpos = (float)(row & (T_SEQ - 1));
          const float ang = tpos * inv;
          const float s = sinf(ang), c = cosf(ang);
          v = v * c + sgn * vp * s;
        }
        Cm[(size_t)row * ldc + col] = v;
      }
    }
  }
}

// ---------------------------------------------------------------------------
// MFMA flash attention. Block = one (b,h,window) = 1024 blocks, 4 waves.
// Wave wv owns query rows [wv*64, wv*64+64). K staged bf16 in LDS [128][64]
// (two 128-key halves), V transposed [64][128]; both XOR-swizzled on 16B
// chunks (conflict-free b128 reads). Per 32-key chunk: S via mfma (A=Q-frags
// from global, B=K-frags), online softmax in C-layout (row=quad*4+reg,
// col=l15; shfl_xor 1/2/4/8 over l15), P->bf16 via per-wave LDS buffer
// (C->A layout transpose, m120 pattern), PV via mfma (B=V^T-frags).
// No barriers inside the chunk loop (per-wave P buffer; in-wave LDS order
// guaranteed by waitcnt). y stays in C-frags; epilogue scales by 1/l and
// writes in-place over the q slot (disjoint rows per wave / cols per h).
// ---------------------------------------------------------------------------
__global__ __launch_bounds__(256, 2)
void attn_mfma(float* __restrict__ qkv) {
  __shared__ unsigned short Ks[128 * 64];   // [key][d], 16 KiB
  __shared__ unsigned short Vt[64 * 128];   // [d][key], 16 KiB
  __shared__ unsigned short Ps[4][64 * 32]; // per-wave P chunk, 16 KiB

  const int w = blockIdx.x, h = blockIdx.y, b = blockIdx.z;
  const int t = threadIdx.x;
  const int lane = t & 63, wv = t >> 6;
  const int l15 = lane & 15, quad = lane >> 4;
  const int t0 = w * WIN;
  const size_t base = ((size_t)b * T_SEQ + t0) * 3072;

  // ---- Q A-frags (fp32 global, rope'd by GEMM epilogue) ----
  short8 qf[4][2];
#pragma unroll
  for (int mt = 0; mt < 4; ++mt) {
    const float* qp = qkv + base + (size_t)(wv * 64 + mt * 16 + l15) * 3072 + h * 64;
#pragma unroll
    for (int ks = 0; ks < 2; ++ks) {
      float4 u0 = *(const float4*)(qp + ks * 32 + quad * 8);
      float4 u1 = *(const float4*)(qp + ks * 32 + quad * 8 + 4);
      uint4 pk;
      pk.x = f2bf(u0.x) | (f2bf(u0.y) << 16);
      pk.y = f2bf(u0.z) | (f2bf(u0.w) << 16);
      pk.z = f2bf(u1.x) | (f2bf(u1.y) << 16);
      pk.w = f2bf(u1.z) | (f2bf(u1.w) << 16);
      qf[mt][ks] = *(short8*)&pk;
    }
  }

  float4v accy[4][4];
#pragma unroll
  for (int i = 0; i < 4; ++i)
#pragma unroll
    for (int j = 0; j < 4; ++j) accy[i][j] = (float4v){0.f, 0.f, 0.f, 0.f};
  float m_[4][4], l_[4][4];
#pragma unroll
  for (int i = 0; i < 4; ++i)
#pragma unroll
    for (int j = 0; j < 4; ++j) { m_[i][j] = -3.0e38f; l_[i][j] = 0.f; }

  for (int half = 0; half < 2; ++half) {
    if (half) __syncthreads();   // all waves done reading previous half
    // ---- stage K half: 128 keys x 64 d. thread t: row t>>1, d-half (t&1)*32
    {
      const int kr = t >> 1, dh = (t & 1) * 32;
      const float* kp = qkv + base + (size_t)(half * 128 + kr) * 3072 + 1024 + h * 64 + dh;
#pragma unroll
      for (int j = 0; j < 4; ++j) {
        float4 u0 = ((const float4*)kp)[2 * j];
        float4 u1 = ((const float4*)kp)[2 * j + 1];
        uint4 pk;
        pk.x = f2bf(u0.x) | (f2bf(u0.y) << 16);
        pk.y = f2bf(u0.z) | (f2bf(u0.w) << 16);
        pk.z = f2bf(u1.x) | (f2bf(u1.y) << 16);
        pk.w = f2bf(u1.z) | (f2bf(u1.w) << 16);
        const int c = (dh >> 3) + j;              // d-chunk 0..7
        *(uint4*)&Ks[kr * 64 + ((c ^ (kr & 7)) * 8)] = pk;
      }
    }
    // ---- stage V^T half: thread t: key pair 2*(t&63), 16 d-values (t>>6)*16
    {
      const int kpair = 2 * (t & 63);
      const int d0 = (t >> 6) * 16;
      const float* v0 = qkv + base + (size_t)(half * 128 + kpair) * 3072 + 2048 + h * 64 + d0;
      const float* v1 = v0 + 3072;
      float4 a0[4], a1[4];
#pragma unroll
      for (int j = 0; j < 4; ++j) { a0[j] = ((const float4*)v0)[j]; a1[j] = ((const float4*)v1)[j]; }
      const int c = kpair >> 3;                   // key-chunk 0..15
#pragma unroll
      for (int j = 0; j < 4; ++j) {
        const float* p0 = (const float*)&a0[j];
        const float* p1 = (const float*)&a1[j];
#pragma unroll
        for (int e = 0; e < 4; ++e) {
          const int d = d0 + 4 * j + e;
          unsigned int pk = f2bf(p0[e]) | (f2bf(p1[e]) << 16);
          *(unsigned int*)&Vt[d * 128 + ((c ^ (d & 7)) * 8) + (kpair & 7)] = pk;
        }
      }
    }
    __syncthreads();

    for (int kc = 0; kc < 4; ++kc) {   // 32-key chunks within half
      // ---- B-frags from K ----
      short8 kf[2][2];
#pragma unroll
      for (int nt = 0; nt < 2; ++nt)
#pragma unroll
        for (int ks = 0; ks < 2; ++ks) {
          const int r = kc * 32 + nt * 16 + l15;
          const int c = ks * 4 + quad;
          kf[nt][ks] = *(const short8*)&Ks[r * 64 + ((c ^ (l15 & 7)) * 8)];
        }
      // ---- S = Q @ K^T ----
      float4v s_[4][2];
#pragma unroll
      for (int mt = 0; mt < 4; ++mt)
#pragma unroll
        for (int nt = 0; nt < 2; ++nt) {
          s_[mt][nt] = __builtin_amdgcn_mfma_f32_16x16x32_bf16(
              qf[mt][0], kf[nt][0], (float4v){0.f, 0.f, 0.f, 0.f}, 0, 0, 0);
          s_[mt][nt] = __builtin_amdgcn_mfma_f32_16x16x32_bf16(
              qf[mt][1], kf[nt][1], s_[mt][nt], 0, 0, 0);
        }
      // ---- online softmax + P write (C->A transpose via LDS) ----
#pragma unroll
      for (int mt = 0; mt < 4; ++mt) {
#pragma unroll
        for (int reg = 0; reg < 4; ++reg) {
          float s0 = s_[mt][0][reg] * SCALE_LOG2E;
          float s1 = s_[mt][1][reg] * SCALE_LOG2E;
          float mx = fmaxf(s0, s1);
          mx = fmaxf(mx, __shfl_xor(mx, 1));
          mx = fmaxf(mx, __shfl_xor(mx, 2));
          mx = fmaxf(mx, __shfl_xor(mx, 4));
          mx = fmaxf(mx, __shfl_xor(mx, 8));
          const float mn = fmaxf(m_[mt][reg], mx);
          const float al = exp2f(m_[mt][reg] - mn);
          const float p0 = exp2f(s0 - mn);
          const float p1 = exp2f(s1 - mn);
          float ps = p0 + p1;
          ps += __shfl_xor(ps, 1);
          ps += __shfl_xor(ps, 2);
          ps += __shfl_xor(ps, 4);
          ps += __shfl_xor(ps, 8);
          l_[mt][reg] = l_[mt][reg] * al + ps;
          m_[mt][reg] = mn;
          // rescale y row
#pragma unroll
          for (int dt = 0; dt < 4; ++dt) accy[mt][dt][reg] *= al;
          // pack adjacent-key pair (l15, l15^1) and write (even lanes)
          const float q0 = __shfl_xor(p0, 1);
          const float q1 = __shfl_xor(p1, 1);
          const unsigned int w0 = f2bf(p0) | (f2bf(q0) << 16);
          const unsigned int w1 = f2bf(p1) | (f2bf(q1) << 16);
          if (!(l15 & 1)) {
            const int row = mt * 16 + quad * 4 + reg;
            const int ca = (0 + (l15 >> 3)) ^ (row & 3);   // nt=0 chunk
            const int cb = (2 + (l15 >> 3)) ^ (row & 3);   // nt=1 chunk
            *(unsigned int*)&Ps[wv][row * 32 + ca * 8 + (l15 & 7)] = w0;
            *(unsigned int*)&Ps[wv][row * 32 + cb * 8 + (l15 & 7)] = w1;
          }
        }
      }
      // ---- P A-frags + V^T B-frags, y += P @ V ----
      short8 pf[4], vf[4];
#pragma unroll
      for (int mt = 0; mt < 4; ++mt) {
        const int row = mt * 16 + l15;
        pf[mt] = *(const short8*)&Ps[wv][row * 32 + ((quad ^ (l15 & 3)) * 8)];
      }
#pragma unroll
      for (int dt = 0; dt < 4; ++dt) {
        const int d = dt * 16 + l15;
        const int c = kc * 4 + quad;
        vf[dt] = *(const short8*)&Vt[d * 128 + ((c ^ (d & 7)) * 8)];
      }
#pragma unroll
      for (int mt = 0; mt < 4; ++mt)
#pragma unroll
        for (int dt = 0; dt < 4; ++dt)
          accy[mt][dt] = __builtin_amdgcn_mfma_f32_16x16x32_bf16(pf[mt], vf[dt],
                                                                 accy[mt][dt], 0, 0, 0);
    }
  }

  // ---- epilogue: y/l -> q slot (in-place) ----
#pragma unroll
  for (int mt = 0; mt < 4; ++mt) {
#pragma unroll
    for (int reg = 0; reg < 4; ++reg) {
      const float rl = 1.f / l_[mt][reg];
      const int row = wv * 64 + mt * 16 + quad * 4 + reg;
      float* yp = qkv + base + (size_t)row * 3072 + h * 64;
#pragma unroll
      for (int dt = 0; dt < 4; ++dt)
        yp[dt * 16 + l15] = accy[mt][dt][reg] * rl;
    }
  }
}

// ---------------------------------------------------------------------------
// ws: qkv fp32 [16384 x 3072] = 192 MiB. W_inT bf16 (6 MiB) in d_out (dead
// until final GEMM). W_outT bf16 (2 MiB) in dead k/v columns of qkv rows
// 0..255 (transposed after attn).
// ---------------------------------------------------------------------------
extern "C" void kernel_launch(void* const* d_in, const int* in_sizes, int n_in,
                              void* d_out, int out_size, void* d_ws, size_t ws_size,
                              hipStream_t stream) {
  const float* x     = (const float*)d_in[0];
  const float* W_in  = (const float*)d_in[1];
  const float* b_in  = (const float*)d_in[2];
  const float* W_out = (const float*)d_in[3];
  const float* b_out = (const float*)d_in[4];
  float* out = (float*)d_out;
  float* qkv = (float*)d_ws;
  unsigned short* winT = (unsigned short*)d_out;

  transpose_cvt<<<dim3(3072 / 32, 1024 / 32), 256, 0, stream>>>(
      W_in, winT, nullptr, 0, 1024, 3072);
  gemm_mfma<<<dim3(3072 / 128, 16384 / 128), 256, 0, stream>>>(
      x, CDIM, winT, nullptr, 0, b_in, qkv, 3 * CDIM, CDIM, 1);
  attn_mfma<<<dim3(T_SEQ / WIN, 16, 4), 256, 0, stream>>>(qkv);
  transpose_cvt<<<dim3(1024 / 32, 1024 / 32), 256, 0, stream>>>(
      W_out, nullptr, qkv, 1, 1024, 1024);
  gemm_mfma<<<dim3(1024 / 128, 16384 / 128), 256, 0, stream>>>(
      qkv, 3 * CDIM, nullptr, qkv, 1, b_out, out, CDIM, CDIM, 0);
}